// Round 4
// baseline (15778.299 us; speedup 1.0000x reference)
//
#include <hip/hip_runtime.h>
#include <math.h>

#define NAGENT 10
#define OBS_D  64
#define HID    50
#define NSYM   10
#define NACT   2
#define NEGV   (-1e9f)

#define TPB 256              // 4 waves share one LDS weight copy
#define WPB 4                // waves per block
#define BPW 6                // batch elements per wave (60 active lanes)
#define BPB (WPB * BPW)      // 24 batch elements per block

#define LD  52               // padded row stride for 50-wide matrices (16B-aligned)
#define CLD 12               // padded W_comm row stride

// LDS / ws layout (floats):
#define OFF_ENC  0           // [64][52]  W_enc
#define OFF_WC0  3328        // [50][52]  W_f0[h] + W_f0[skip]   (h==h0 at step 0)
#define OFF_W1S  5928        // [50][52]  W_f1[skip]
#define OFF_W1H  8528        // [50][52]  W_f1[h]
#define OFF_WC0c 11128       // [10][52]  W_f0[c]
#define OFF_W1c  11648       // [10][52]  W_f1[c]
#define OFF_WCM  12168       // [50][12]  W_comm
#define OFF_WPI  12768       // [50][2]   W_pi
#define OFF_WV   12868       // [50]      W_v
#define OFF_BENC 12918       // [50]      b_enc
#define OFF_BF   12968       // [2][50]   b_f
#define OFF_BCM  13068       // [10]      b_comm
#define OFF_BPI  13078       // [2]       b_pi
#define OFF_BV   13080       // [1]       b_v
#define NPREP    13084       // padded to x4 -> 52336 B of LDS

__device__ __forceinline__ float fast_tanh(float x) {
  float xc = fminf(15.f, fmaxf(-15.f, x));
  float e  = __expf(2.f * xc);
  return __fdividef(e - 1.f, e + 1.f);
}

__global__ void prep_weights(const float* __restrict__ W_enc,
                             const float* __restrict__ W_f,
                             const float* __restrict__ W_comm,
                             const float* __restrict__ W_pi,
                             const float* __restrict__ W_v,
                             const float* __restrict__ b_enc,
                             const float* __restrict__ b_f,
                             const float* __restrict__ b_comm,
                             const float* __restrict__ b_pi,
                             const float* __restrict__ b_v,
                             float* __restrict__ ws) {
  int i = blockIdx.x * blockDim.x + threadIdx.x;
  if (i >= NPREP) return;
  float v = 0.f;
  if (i < OFF_WCM) {
    int j = i % LD, r = i / LD;
    if (j < HID) {
      if      (r <  64)                 { v = W_enc[r*HID + j]; }
      else if (r < 114) { int k = r-64;   v = W_f[k*HID + j] + W_f[(60+k)*HID + j]; }
      else if (r < 164) { int k = r-114;  v = W_f[(110+60+k)*HID + j]; }
      else if (r < 214) { int k = r-164;  v = W_f[(110+k)*HID + j]; }
      else if (r < 224) { int s = r-214;  v = W_f[(50+s)*HID + j]; }
      else              { int s = r-224;  v = W_f[(110+50+s)*HID + j]; }
    }
  } else if (i < OFF_WPI) {
    int r = (i - OFF_WCM) / CLD, j = (i - OFF_WCM) % CLD;
    v = (j < NSYM) ? W_comm[r*NSYM + j] : 0.f;
  } else if (i < OFF_WV)   { v = W_pi [i - OFF_WPI];
  } else if (i < OFF_BENC) { v = W_v  [i - OFF_WV];
  } else if (i < OFF_BF)   { v = b_enc[i - OFF_BENC];
  } else if (i < OFF_BCM)  { v = b_f  [i - OFF_BF];
  } else if (i < OFF_BPI)  { v = b_comm[i - OFF_BCM];
  } else if (i < OFF_BV)   { v = b_pi [i - OFF_BPI];
  } else if (i == OFF_BV)  { v = b_v[0]; }
  ws[i] = v;
}

// masked log-softmax argmax: applies mask, returns argmax, adds comm_logp term.
__device__ __forceinline__ int comm_pick(float cl[NSYM], float mk, float& clp) {
  #pragma unroll
  for (int s = 0; s < NSYM; s++) cl[s] = (mk == 0.f) ? NEGV : cl[s];
  int w = 0; float best = cl[0];
  #pragma unroll
  for (int s = 1; s < NSYM; s++) { bool b = cl[s] > best; best = b ? cl[s] : best; w = b ? s : w; }
  float se = 0.f;
  #pragma unroll
  for (int s = 0; s < NSYM; s++) se += __expf(cl[s] - best);
  clp += (-__logf(se)) * mk;
  return w;
}

__global__ __launch_bounds__(TPB) __attribute__((amdgpu_waves_per_eu(2, 4)))
void policy_kernel(const float* __restrict__ obs,
                   const float* __restrict__ mask,
                   const float* __restrict__ wsP,
                   float* __restrict__ out,
                   int B)
{
  __shared__ __align__(16) float lw[NPREP];
  const int t = threadIdx.x;

  // ---- stage all weights/biases into LDS (float4, coalesced), one barrier
  {
    const float4* src = (const float4*)wsP;
    float4* dst = (float4*)lw;
    #pragma unroll 2
    for (int i = t; i < NPREP / 4; i += TPB) dst[i] = src[i];
  }
  __syncthreads();   // the only barrier; all later phases are wave-local

  const int lane = t & 63;
  const int wv   = t >> 6;
  const int beW  = blockIdx.x * BPB + wv * BPW;   // this wave's first batch element
  const int bel  = lane / NAGENT;                 // element-in-wave 0..5 (6 for lanes>=60)
  const int aidx = lane % NAGENT;
  const long long NA = (long long)B * NAGENT;
  const bool act = (lane < BPW * NAGENT) && (beW + bel < B);
  const long long g  = (long long)(beW + bel) * NAGENT + aidx;
  const long long gc = act ? g : 0;
  const int sh = bel * NAGENT;

  const float mk = mask[gc];
  float h[HID];                                   // current hidden state (registers)

  // ================= enc: h0 = tanh(obs @ W_enc + b_enc) =================
  {
    float acc[HID];
    #pragma unroll
    for (int j = 0; j < HID; j++) acc[j] = lw[OFF_BENC + j];
    const float4* o4 = (const float4*)(obs + gc * OBS_D);
    #pragma unroll
    for (int q = 0; q < OBS_D / 4; q++) {
      float4 v = o4[q];
      const float* wr = &lw[OFF_ENC + q * 4 * LD];
      #pragma unroll
      for (int j = 0; j < HID; j++) acc[j] = fmaf(v.x, wr[j], acc[j]);
      #pragma unroll
      for (int j = 0; j < HID; j++) acc[j] = fmaf(v.y, wr[LD + j], acc[j]);
      #pragma unroll
      for (int j = 0; j < HID; j++) acc[j] = fmaf(v.z, wr[2 * LD + j], acc[j]);
      #pragma unroll
      for (int j = 0; j < HID; j++) acc[j] = fmaf(v.w, wr[3 * LD + j], acc[j]);
    }
    #pragma unroll
    for (int j = 0; j < HID; j++) h[j] = fast_tanh(acc[j]);
  }

  // ================= step 0 comm head =================
  float clp = 0.f;
  float c_reg[NSYM];
  int w;
  {
    float cl[NSYM];
    #pragma unroll
    for (int s = 0; s < NSYM; s++) cl[s] = lw[OFF_BCM + s];
    #pragma unroll
    for (int k = 0; k < HID; k++) {
      float x = h[k];
      const float* wr = &lw[OFF_WCM + k * CLD];
      #pragma unroll
      for (int s = 0; s < NSYM; s++) cl[s] = fmaf(x, wr[s], cl[s]);
    }
    w = comm_pick(cl, mk, clp);
  }
  #pragma unroll
  for (int s = 0; s < NSYM; s++) {
    unsigned long long b = __ballot(w == s);
    c_reg[s] = ((b >> sh) & 0x3FFULL) ? 1.f : 0.f;
  }

  // ===== phase 2: acc = b_f0 + c0 @ W_f0[c] + h0 @ (W_f0[h]+W_f0[skip]) =====
  float acc[HID];
  #pragma unroll
  for (int j = 0; j < HID; j++) acc[j] = lw[OFF_BF + j];
  #pragma unroll
  for (int s = 0; s < NSYM; s++) {
    float cv = c_reg[s];
    const float* wr = &lw[OFF_WC0c + s * LD];
    #pragma unroll
    for (int j = 0; j < HID; j++) acc[j] = fmaf(cv, wr[j], acc[j]);
  }
  #pragma unroll
  for (int k = 0; k < HID; k++) {
    float x = h[k];
    const float* wr = &lw[OFF_WC0 + k * LD];
    #pragma unroll
    for (int j = 0; j < HID; j++) acc[j] = fmaf(x, wr[j], acc[j]);
  }

  // ===== phase 2.5: pre1 = b_f1 + h0 @ W_f1[skip]   (h0's last use) =====
  float pre1[HID];
  #pragma unroll
  for (int j = 0; j < HID; j++) pre1[j] = lw[OFF_BF + HID + j];
  #pragma unroll
  for (int k = 0; k < HID; k++) {
    float x = h[k];
    const float* wr = &lw[OFF_W1S + k * LD];
    #pragma unroll
    for (int j = 0; j < HID; j++) pre1[j] = fmaf(x, wr[j], pre1[j]);
  }

  // h <- h1 (h0 regs die here)
  #pragma unroll
  for (int j = 0; j < HID; j++) h[j] = fast_tanh(acc[j]);

  // ================= step 1 comm head =================
  {
    float cl[NSYM];
    #pragma unroll
    for (int s = 0; s < NSYM; s++) cl[s] = lw[OFF_BCM + s];
    #pragma unroll
    for (int k = 0; k < HID; k++) {
      float x = h[k];
      const float* wr = &lw[OFF_WCM + k * CLD];
      #pragma unroll
      for (int s = 0; s < NSYM; s++) cl[s] = fmaf(x, wr[s], cl[s]);
    }
    w = comm_pick(cl, mk, clp);
  }
  #pragma unroll
  for (int s = 0; s < NSYM; s++) {
    unsigned long long b = __ballot(w == s);
    c_reg[s] = ((b >> sh) & 0x3FFULL) ? 1.f : 0.f;   // step-1 c (also output c)
  }

  // ===== phase 4: pre1 += c1 @ W_f1[c] + h1 @ W_f1[h]; h2 = tanh; heads =====
  #pragma unroll
  for (int s = 0; s < NSYM; s++) {
    float cv = c_reg[s];
    const float* wr = &lw[OFF_W1c + s * LD];
    #pragma unroll
    for (int j = 0; j < HID; j++) pre1[j] = fmaf(cv, wr[j], pre1[j]);
  }
  #pragma unroll
  for (int k = 0; k < HID; k++) {
    float x = h[k];
    const float* wr = &lw[OFF_W1H + k * LD];
    #pragma unroll
    for (int j = 0; j < HID; j++) pre1[j] = fmaf(x, wr[j], pre1[j]);
  }

  float l0 = lw[OFF_BPI], l1 = lw[OFF_BPI + 1], bv = lw[OFF_BV];
  #pragma unroll
  for (int j = 0; j < HID; j++) {
    float hh = fast_tanh(pre1[j]);
    l0 = fmaf(hh, lw[OFF_WPI + j * 2 + 0], l0);
    l1 = fmaf(hh, lw[OFF_WPI + j * 2 + 1], l1);
    bv = fmaf(hh, lw[OFF_WV + j], bv);
  }

  if (act) {
    float2* o2 = (float2*)out;
    o2[g] = make_float2((mk == 0.f) ? NEGV : l0, (mk == 0.f) ? NEGV : l1);
    out[NA * 2 + g] = bv * mk;
    out[NA * 3 + g] = clp;
    float2* c2 = (float2*)(out + NA * 4);
    const long long cb = g * (NSYM / 2);
    #pragma unroll
    for (int s = 0; s < NSYM / 2; s++)
      c2[cb + s] = make_float2(c_reg[2 * s], c_reg[2 * s + 1]);
  }
}

extern "C" void kernel_launch(void* const* d_in, const int* in_sizes, int n_in,
                              void* d_out, int out_size, void* d_ws, size_t ws_size,
                              hipStream_t stream) {
  const float* obs    = (const float*)d_in[0];
  const float* mask   = (const float*)d_in[1];
  const float* W_enc  = (const float*)d_in[2];
  const float* b_enc  = (const float*)d_in[3];
  const float* W_f    = (const float*)d_in[4];
  const float* b_f    = (const float*)d_in[5];
  const float* W_comm = (const float*)d_in[6];
  const float* b_comm = (const float*)d_in[7];
  const float* W_pi   = (const float*)d_in[8];
  const float* b_pi   = (const float*)d_in[9];
  const float* W_v    = (const float*)d_in[10];
  const float* b_v    = (const float*)d_in[11];
  float* out = (float*)d_out;
  float* ws  = (float*)d_ws;

  const int B = in_sizes[0] / (NAGENT * OBS_D);

  hipLaunchKernelGGL(prep_weights, dim3((NPREP + 255) / 256), dim3(256), 0, stream,
                     W_enc, W_f, W_comm, W_pi, W_v, b_enc, b_f, b_comm, b_pi, b_v, ws);

  const int grid = (B + BPB - 1) / BPB;
  hipLaunchKernelGGL(policy_kernel, dim3(grid), dim3(TPB), 0, stream,
                     obs, mask, ws, out, B);
}

// Round 5
// 8511.812 us; speedup vs baseline: 1.8537x; 1.8537x over previous
//
#include <hip/hip_runtime.h>
#include <math.h>

#define NAGENT 10
#define OBS_D  64
#define HID    50
#define NSYM   10
#define NACT   2
#define NEGV   (-1e9f)

#define TPB 256              // 4 waves share one LDS weight copy
#define WPB 4                // waves per block
#define BPW 6                // batch elements per wave (60 active lanes)
#define BPB (WPB * BPW)      // 24 batch elements per block

#define LD  52               // padded row stride for 50-wide matrices (16B-aligned)
#define CLD 12               // padded W_comm row stride

// LDS / ws layout (floats):
#define OFF_ENC  0           // [64][52]  W_enc
#define OFF_WC0  3328        // [50][52]  W_f0[h] + W_f0[skip]   (h==h0 at step 0)
#define OFF_W1S  5928        // [50][52]  W_f1[skip]
#define OFF_W1H  8528        // [50][52]  W_f1[h]
#define OFF_WC0c 11128       // [10][52]  W_f0[c]
#define OFF_W1c  11648       // [10][52]  W_f1[c]
#define OFF_WCM  12168       // [50][12]  W_comm
#define OFF_WPI  12768       // [50][2]   W_pi
#define OFF_WV   12868       // [50]      W_v
#define OFF_BENC 12918       // [50]      b_enc
#define OFF_BF   12968       // [2][50]   b_f
#define OFF_BCM  13068       // [10]      b_comm
#define OFF_BPI  13078       // [2]       b_pi
#define OFF_BV   13080       // [1]       b_v
#define NPREP    13084       // padded to x4 -> 52336 B of LDS
static_assert(NPREP % 4 == 0, "pad");

__device__ __forceinline__ float fast_tanh(float x) {
  float xc = fminf(15.f, fmaxf(-15.f, x));
  float e  = __expf(2.f * xc);
  return __fdividef(e - 1.f, e + 1.f);
}

__global__ void prep_weights(const float* __restrict__ W_enc,
                             const float* __restrict__ W_f,
                             const float* __restrict__ W_comm,
                             const float* __restrict__ W_pi,
                             const float* __restrict__ W_v,
                             const float* __restrict__ b_enc,
                             const float* __restrict__ b_f,
                             const float* __restrict__ b_comm,
                             const float* __restrict__ b_pi,
                             const float* __restrict__ b_v,
                             float* __restrict__ ws) {
  int i = blockIdx.x * blockDim.x + threadIdx.x;
  if (i >= NPREP) return;
  float v = 0.f;
  if (i < OFF_WCM) {
    int j = i % LD, r = i / LD;
    if (j < HID) {
      if      (r <  64)                 { v = W_enc[r*HID + j]; }
      else if (r < 114) { int k = r-64;   v = W_f[k*HID + j] + W_f[(60+k)*HID + j]; }
      else if (r < 164) { int k = r-114;  v = W_f[(110+60+k)*HID + j]; }
      else if (r < 214) { int k = r-164;  v = W_f[(110+k)*HID + j]; }
      else if (r < 224) { int s = r-214;  v = W_f[(50+s)*HID + j]; }
      else              { int s = r-224;  v = W_f[(110+50+s)*HID + j]; }
    }
  } else if (i < OFF_WPI) {
    int r = (i - OFF_WCM) / CLD, j = (i - OFF_WCM) % CLD;
    v = (j < NSYM) ? W_comm[r*NSYM + j] : 0.f;
  } else if (i < OFF_WV)   { v = W_pi [i - OFF_WPI];
  } else if (i < OFF_BENC) { v = W_v  [i - OFF_WV];
  } else if (i < OFF_BF)   { v = b_enc[i - OFF_BENC];
  } else if (i < OFF_BCM)  { v = b_f  [i - OFF_BF];
  } else if (i < OFF_BPI)  { v = b_comm[i - OFF_BCM];
  } else if (i < OFF_BV)   { v = b_pi [i - OFF_BPI];
  } else if (i == OFF_BV)  { v = b_v[0]; }
  ws[i] = v;
}

// masked log-softmax argmax: applies mask, returns argmax, adds comm_logp term.
__device__ __forceinline__ int comm_pick(float cl[NSYM], float mk, float& clp) {
  #pragma unroll
  for (int s = 0; s < NSYM; s++) cl[s] = (mk == 0.f) ? NEGV : cl[s];
  int w = 0; float best = cl[0];
  #pragma unroll
  for (int s = 1; s < NSYM; s++) { bool b = cl[s] > best; best = b ? cl[s] : best; w = b ? s : w; }
  float se = 0.f;
  #pragma unroll
  for (int s = 0; s < NSYM; s++) se += __expf(cl[s] - best);
  clp += (-__logf(se)) * mk;
  return w;
}

__global__ __launch_bounds__(TPB)
void policy_kernel(const float* __restrict__ obs,
                   const float* __restrict__ mask,
                   const float* __restrict__ wsP,
                   float* __restrict__ out,
                   int B)
{
  __shared__ __align__(16) float lw[NPREP];
  const int t = threadIdx.x;

  // ---- stage all weights/biases into LDS (float4, coalesced), one barrier
  {
    const float4* src = (const float4*)wsP;
    float4* dst = (float4*)lw;
    #pragma unroll 2
    for (int i = t; i < NPREP / 4; i += TPB) dst[i] = src[i];
  }
  __syncthreads();   // the only barrier; all later phases are wave-local

  const int lane = t & 63;
  const int wv   = t >> 6;
  const int beW  = blockIdx.x * BPB + wv * BPW;   // this wave's first batch element
  const int bel  = lane / NAGENT;                 // element-in-wave 0..5 (6 for lanes>=60)
  const int aidx = lane % NAGENT;
  const long long NA = (long long)B * NAGENT;
  const bool act = (lane < BPW * NAGENT) && (beW + bel < B);
  const long long g  = (long long)(beW + bel) * NAGENT + aidx;
  const long long gc = act ? g : 0;
  const int sh = bel * NAGENT;

  const float mk = mask[gc];
  float h0[HID];                                  // persists to the end
  float h1[HID];                                  // persists to the end

  // ================= enc: h0 = tanh(obs @ W_enc + b_enc) =================
  {
    float acc[HID];
    #pragma unroll
    for (int j = 0; j < HID; j++) acc[j] = lw[OFF_BENC + j];
    const float4* o4 = (const float4*)(obs + gc * OBS_D);
    #pragma unroll
    for (int half = 0; half < 2; half++) {
      float4 ob[8];                               // 32 obs floats in flight (vmcnt)
      #pragma unroll
      for (int q = 0; q < 8; q++) ob[q] = o4[half * 8 + q];
      #pragma unroll
      for (int q = 0; q < 8; q++) {
        const float* wr = &lw[OFF_ENC + (half * 32 + q * 4) * LD];
        #pragma unroll
        for (int j = 0; j < HID; j++) acc[j] = fmaf(ob[q].x, wr[j], acc[j]);
        #pragma unroll
        for (int j = 0; j < HID; j++) acc[j] = fmaf(ob[q].y, wr[LD + j], acc[j]);
        #pragma unroll
        for (int j = 0; j < HID; j++) acc[j] = fmaf(ob[q].z, wr[2 * LD + j], acc[j]);
        #pragma unroll
        for (int j = 0; j < HID; j++) acc[j] = fmaf(ob[q].w, wr[3 * LD + j], acc[j]);
      }
    }
    #pragma unroll
    for (int j = 0; j < HID; j++) h0[j] = fast_tanh(acc[j]);
  }

  // ================= step 0 comm head (on h0) =================
  float clp = 0.f;
  float c_reg[NSYM];
  int w;
  {
    float cl[NSYM];
    #pragma unroll
    for (int s = 0; s < NSYM; s++) cl[s] = lw[OFF_BCM + s];
    #pragma unroll
    for (int k = 0; k < HID; k++) {
      float x = h0[k];
      const float* wr = &lw[OFF_WCM + k * CLD];
      #pragma unroll
      for (int s = 0; s < NSYM; s++) cl[s] = fmaf(x, wr[s], cl[s]);
    }
    w = comm_pick(cl, mk, clp);
  }
  #pragma unroll
  for (int s = 0; s < NSYM; s++) {
    unsigned long long b = __ballot(w == s);
    c_reg[s] = ((b >> sh) & 0x3FFULL) ? 1.f : 0.f;
  }

  // ===== phase 2: h1 = tanh(b_f0 + c0 @ W_f0[c] + h0 @ (W_f0[h]+W_f0[skip])) =====
  {
    float acc[HID];
    #pragma unroll
    for (int j = 0; j < HID; j++) acc[j] = lw[OFF_BF + j];
    #pragma unroll
    for (int s = 0; s < NSYM; s++) {
      float cv = c_reg[s];
      const float* wr = &lw[OFF_WC0c + s * LD];
      #pragma unroll
      for (int j = 0; j < HID; j++) acc[j] = fmaf(cv, wr[j], acc[j]);
    }
    #pragma unroll
    for (int k = 0; k < HID; k++) {
      float x = h0[k];
      const float* wr = &lw[OFF_WC0 + k * LD];
      #pragma unroll
      for (int j = 0; j < HID; j++) acc[j] = fmaf(x, wr[j], acc[j]);
    }
    #pragma unroll
    for (int j = 0; j < HID; j++) h1[j] = fast_tanh(acc[j]);
  }

  // ================= step 1 comm head (on h1) =================
  {
    float cl[NSYM];
    #pragma unroll
    for (int s = 0; s < NSYM; s++) cl[s] = lw[OFF_BCM + s];
    #pragma unroll
    for (int k = 0; k < HID; k++) {
      float x = h1[k];
      const float* wr = &lw[OFF_WCM + k * CLD];
      #pragma unroll
      for (int s = 0; s < NSYM; s++) cl[s] = fmaf(x, wr[s], cl[s]);
    }
    w = comm_pick(cl, mk, clp);
  }
  #pragma unroll
  for (int s = 0; s < NSYM; s++) {
    unsigned long long b = __ballot(w == s);
    c_reg[s] = ((b >> sh) & 0x3FFULL) ? 1.f : 0.f;   // step-1 c (also output c)
  }

  // ===== phase 4, 25-wide chunks: pre = b_f1 + c1@W1c + h0@W1S + h1@W1H =====
  // chunking caps peak live regs at h0(50)+h1(50)+pre(25)+misc
  float l0 = lw[OFF_BPI], l1 = lw[OFF_BPI + 1], bv = lw[OFF_BV];
  #pragma unroll
  for (int c0 = 0; c0 < HID; c0 += 25) {
    float pre[25];
    #pragma unroll
    for (int j = 0; j < 25; j++) pre[j] = lw[OFF_BF + HID + c0 + j];
    #pragma unroll
    for (int s = 0; s < NSYM; s++) {
      float cv = c_reg[s];
      const float* wr = &lw[OFF_W1c + s * LD + c0];
      #pragma unroll
      for (int j = 0; j < 25; j++) pre[j] = fmaf(cv, wr[j], pre[j]);
    }
    #pragma unroll
    for (int k = 0; k < HID; k++) {
      float x = h0[k];
      const float* wr = &lw[OFF_W1S + k * LD + c0];
      #pragma unroll
      for (int j = 0; j < 25; j++) pre[j] = fmaf(x, wr[j], pre[j]);
    }
    #pragma unroll
    for (int k = 0; k < HID; k++) {
      float x = h1[k];
      const float* wr = &lw[OFF_W1H + k * LD + c0];
      #pragma unroll
      for (int j = 0; j < 25; j++) pre[j] = fmaf(x, wr[j], pre[j]);
    }
    #pragma unroll
    for (int j = 0; j < 25; j++) {
      float hh = fast_tanh(pre[j]);
      l0 = fmaf(hh, lw[OFF_WPI + (c0 + j) * 2 + 0], l0);
      l1 = fmaf(hh, lw[OFF_WPI + (c0 + j) * 2 + 1], l1);
      bv = fmaf(hh, lw[OFF_WV + c0 + j], bv);
    }
  }

  if (act) {
    float2* o2 = (float2*)out;
    o2[g] = make_float2((mk == 0.f) ? NEGV : l0, (mk == 0.f) ? NEGV : l1);
    out[NA * 2 + g] = bv * mk;
    out[NA * 3 + g] = clp;
    float2* c2 = (float2*)(out + NA * 4);
    const long long cb = g * (NSYM / 2);
    #pragma unroll
    for (int s = 0; s < NSYM / 2; s++)
      c2[cb + s] = make_float2(c_reg[2 * s], c_reg[2 * s + 1]);
  }
}

extern "C" void kernel_launch(void* const* d_in, const int* in_sizes, int n_in,
                              void* d_out, int out_size, void* d_ws, size_t ws_size,
                              hipStream_t stream) {
  const float* obs    = (const float*)d_in[0];
  const float* mask   = (const float*)d_in[1];
  const float* W_enc  = (const float*)d_in[2];
  const float* b_enc  = (const float*)d_in[3];
  const float* W_f    = (const float*)d_in[4];
  const float* b_f    = (const float*)d_in[5];
  const float* W_comm = (const float*)d_in[6];
  const float* b_comm = (const float*)d_in[7];
  const float* W_pi   = (const float*)d_in[8];
  const float* b_pi   = (const float*)d_in[9];
  const float* W_v    = (const float*)d_in[10];
  const float* b_v    = (const float*)d_in[11];
  float* out = (float*)d_out;
  float* ws  = (float*)d_ws;

  const int B = in_sizes[0] / (NAGENT * OBS_D);

  hipLaunchKernelGGL(prep_weights, dim3((NPREP + 255) / 256), dim3(256), 0, stream,
                     W_enc, W_f, W_comm, W_pi, W_v, b_enc, b_f, b_comm, b_pi, b_v, ws);

  const int grid = (B + BPB - 1) / BPB;
  hipLaunchKernelGGL(policy_kernel, dim3(grid), dim3(TPB), 0, stream,
                     obs, mask, ws, out, B);
}

// Round 6
// 867.093 us; speedup vs baseline: 18.1968x; 9.8165x over previous
//
#include <hip/hip_runtime.h>
#include <math.h>

#define NAGENT 10
#define OBS_D  64
#define HID    50
#define NSYM   10
#define NEGV   (-1e9f)

#define TPB 64               // one wave per block
#define BPW 6                // batch elements per block (60 active lanes)
#define AG  60

#define LD  52               // padded row stride for 50-wide matrices
#define CLD 12               // padded W_comm row stride

// ws layout (floats), identical to R5 prep:
#define OFF_ENC  0           // [64][52]  W_enc
#define OFF_WC0  3328        // [50][52]  W_f0[h] + W_f0[skip]
#define OFF_W1S  5928        // [50][52]  W_f1[skip]
#define OFF_W1H  8528        // [50][52]  W_f1[h]
#define OFF_WC0c 11128       // [10][52]  W_f0[c]
#define OFF_W1c  11648       // [10][52]  W_f1[c]
#define OFF_WCM  12168       // [50][12]  W_comm
#define OFF_WPI  12768       // [50][2]   W_pi
#define OFF_WV   12868       // [50]      W_v
#define OFF_BENC 12918       // [50]      b_enc
#define OFF_BF   12968       // [2][50]   b_f
#define OFF_BCM  13068       // [10]      b_comm
#define OFF_BPI  13078       // [2]       b_pi
#define OFF_BV   13080       // [1]       b_v
#define NPREP    13084

typedef float v2f __attribute__((ext_vector_type(2)));

__device__ __forceinline__ v2f pk_fma(v2f a, v2f b, v2f c) {
  v2f d;
  asm("v_pk_fma_f32 %0, %1, %2, %3" : "=v"(d) : "v"(a), "v"(b), "v"(c));
  return d;
}

__device__ __forceinline__ float fast_tanh(float x) {
  float xc = fminf(15.f, fmaxf(-15.f, x));
  float e  = __expf(2.f * xc);
  return __fdividef(e - 1.f, e + 1.f);
}

__global__ void prep_weights(const float* __restrict__ W_enc,
                             const float* __restrict__ W_f,
                             const float* __restrict__ W_comm,
                             const float* __restrict__ W_pi,
                             const float* __restrict__ W_v,
                             const float* __restrict__ b_enc,
                             const float* __restrict__ b_f,
                             const float* __restrict__ b_comm,
                             const float* __restrict__ b_pi,
                             const float* __restrict__ b_v,
                             float* __restrict__ ws) {
  int i = blockIdx.x * blockDim.x + threadIdx.x;
  if (i >= NPREP) return;
  float v = 0.f;
  if (i < OFF_WCM) {
    int j = i % LD, r = i / LD;
    if (j < HID) {
      if      (r <  64)                 { v = W_enc[r*HID + j]; }
      else if (r < 114) { int k = r-64;   v = W_f[k*HID + j] + W_f[(60+k)*HID + j]; }
      else if (r < 164) { int k = r-114;  v = W_f[(110+60+k)*HID + j]; }
      else if (r < 214) { int k = r-164;  v = W_f[(110+k)*HID + j]; }
      else if (r < 224) { int s = r-214;  v = W_f[(50+s)*HID + j]; }
      else              { int s = r-224;  v = W_f[(110+50+s)*HID + j]; }
    }
  } else if (i < OFF_WPI) {
    int r = (i - OFF_WCM) / CLD, j = (i - OFF_WCM) % CLD;
    v = (j < NSYM) ? W_comm[r*NSYM + j] : 0.f;
  } else if (i < OFF_WV)   { v = W_pi [i - OFF_WPI];
  } else if (i < OFF_BENC) { v = W_v  [i - OFF_WV];
  } else if (i < OFF_BF)   { v = b_enc[i - OFF_BENC];
  } else if (i < OFF_BCM)  { v = b_f  [i - OFF_BF];
  } else if (i < OFF_BPI)  { v = b_comm[i - OFF_BCM];
  } else if (i < OFF_BV)   { v = b_pi [i - OFF_BPI];
  } else if (i == OFF_BV)  { v = b_v[0]; }
  ws[i] = v;
}

// masked log-softmax argmax: applies mask, returns argmax, adds comm_logp term.
__device__ __forceinline__ int comm_pick(float cl[NSYM], float mk, float& clp) {
  #pragma unroll
  for (int s = 0; s < NSYM; s++) cl[s] = (mk == 0.f) ? NEGV : cl[s];
  int w = 0; float best = cl[0];
  #pragma unroll
  for (int s = 1; s < NSYM; s++) { bool b = cl[s] > best; best = b ? cl[s] : best; w = b ? s : w; }
  float se = 0.f;
  #pragma unroll
  for (int s = 0; s < NSYM; s++) se += __expf(cl[s] - best);
  clp += (-__logf(se)) * mk;
  return w;
}

__global__ __launch_bounds__(TPB)
void policy_kernel(const float* __restrict__ obs,
                   const float* __restrict__ mask,
                   const float* __restrict__ wsP,
                   float* __restrict__ out,
                   int B)
{
  __shared__ float hbuf[TPB * 51];          // per-lane h row, stride 51 (2-way, free)
  const int t = threadIdx.x;

  // divergence-poison: runtime 0 the compiler can't prove uniform ->
  // every weight access stays a VMEM (global) load, never s_load.
  const int dv = __builtin_amdgcn_ds_bpermute(0, 0);
  const float* W = wsP + dv;

  const int beW  = blockIdx.x * BPW;
  const int bel  = t / NAGENT;              // 0..5 (6 for lanes 60-63)
  const int aidx = t % NAGENT;
  const long long NA = (long long)B * NAGENT;
  const bool act = (t < AG) && (beW + bel < B);
  const long long g  = (long long)(beW + bel) * NAGENT + aidx;
  const long long gc = act ? g : 0;
  const int sh = bel * NAGENT;

  const float mk = mask[gc];
  float* myh = &hbuf[t * 51];

  // ================= enc: h0 = tanh(obs @ W_enc + b_enc) =================
  v2f acc2[25];
  {
    const v2f* bp = (const v2f*)(W + OFF_BENC);
    #pragma unroll
    for (int j = 0; j < 25; j++) acc2[j] = bp[j];
    const float4* o4 = (const float4*)(obs + gc * OBS_D);
    #pragma unroll
    for (int half = 0; half < 2; half++) {
      float4 ob[8];
      #pragma unroll
      for (int q = 0; q < 8; q++) ob[q] = o4[half * 8 + q];
      #pragma unroll
      for (int q = 0; q < 8; q++) {
        const v2f* wr = (const v2f*)(W + OFF_ENC + (half * 32 + q * 4) * LD);
        v2f xx;
        xx.x = ob[q].x; xx.y = ob[q].x;
        #pragma unroll
        for (int j = 0; j < 25; j++) acc2[j] = pk_fma(wr[j], xx, acc2[j]);
        xx.x = ob[q].y; xx.y = ob[q].y;
        #pragma unroll
        for (int j = 0; j < 25; j++) acc2[j] = pk_fma(wr[26 + j], xx, acc2[j]);
        xx.x = ob[q].z; xx.y = ob[q].z;
        #pragma unroll
        for (int j = 0; j < 25; j++) acc2[j] = pk_fma(wr[52 + j], xx, acc2[j]);
        xx.x = ob[q].w; xx.y = ob[q].w;
        #pragma unroll
        for (int j = 0; j < 25; j++) acc2[j] = pk_fma(wr[78 + j], xx, acc2[j]);
      }
    }
  }

  // ===== tanh -> h0 (LDS row) fused with step-0 comm head =====
  float clp = 0.f;
  v2f cl2[5];
  {
    const v2f* bcm = (const v2f*)(W + OFF_BCM);
    #pragma unroll
    for (int i = 0; i < 5; i++) cl2[i] = bcm[i];
    #pragma unroll
    for (int p = 0; p < 25; p++) {
      float ha = fast_tanh(acc2[p].x);
      float hb = fast_tanh(acc2[p].y);
      myh[2 * p]     = ha;
      myh[2 * p + 1] = hb;
      const v2f* wra = (const v2f*)(W + OFF_WCM + (2 * p) * CLD);
      const v2f* wrb = (const v2f*)(W + OFF_WCM + (2 * p + 1) * CLD);
      v2f xa; xa.x = ha; xa.y = ha;
      v2f xb; xb.x = hb; xb.y = hb;
      #pragma unroll
      for (int i = 0; i < 5; i++) cl2[i] = pk_fma(wra[i], xa, cl2[i]);
      #pragma unroll
      for (int i = 0; i < 5; i++) cl2[i] = pk_fma(wrb[i], xb, cl2[i]);
    }
  }

  // ---- step 0: pick symbol, aggregate c via wave ballot
  float c_reg[NSYM];
  int w;
  {
    float cl[NSYM];
    #pragma unroll
    for (int i = 0; i < 5; i++) { cl[2 * i] = cl2[i].x; cl[2 * i + 1] = cl2[i].y; }
    w = comm_pick(cl, mk, clp);
  }
  #pragma unroll
  for (int s = 0; s < NSYM; s++) {
    unsigned long long b = __ballot(w == s);
    c_reg[s] = ((b >> sh) & 0x3FFULL) ? 1.f : 0.f;
  }

  // ===== (b) acc2 = b_f0 + c0 @ W_f0[c] + h0 @ (W_f0[h]+W_f0[skip]) =====
  {
    const v2f* bf0 = (const v2f*)(W + OFF_BF);
    #pragma unroll
    for (int j = 0; j < 25; j++) acc2[j] = bf0[j];
    #pragma unroll
    for (int s = 0; s < NSYM; s++) {
      v2f cv; cv.x = c_reg[s]; cv.y = c_reg[s];
      const v2f* wr = (const v2f*)(W + OFF_WC0c + s * LD);
      #pragma unroll
      for (int j = 0; j < 25; j++) acc2[j] = pk_fma(wr[j], cv, acc2[j]);
    }
    #pragma unroll 2
    for (int k = 0; k < HID; k++) {
      float x = myh[k];
      v2f xx; xx.x = x; xx.y = x;
      const v2f* wr = (const v2f*)(W + OFF_WC0 + k * LD);
      #pragma unroll
      for (int j = 0; j < 25; j++) acc2[j] = pk_fma(wr[j], xx, acc2[j]);
    }
  }

  // ===== (a) pre2 = b_f1 + h0 @ W_f1[skip]   (h0's last use) =====
  v2f pre2[25];
  {
    const v2f* bf1 = (const v2f*)(W + OFF_BF + HID);
    #pragma unroll
    for (int j = 0; j < 25; j++) pre2[j] = bf1[j];
    #pragma unroll 2
    for (int k = 0; k < HID; k++) {
      float x = myh[k];
      v2f xx; xx.x = x; xx.y = x;
      const v2f* wr = (const v2f*)(W + OFF_W1S + k * LD);
      #pragma unroll
      for (int j = 0; j < 25; j++) pre2[j] = pk_fma(wr[j], xx, pre2[j]);
    }
  }

  // ===== tanh -> h1 (overwrites LDS row; lane-private) fused with step-1 comm head =====
  {
    const v2f* bcm = (const v2f*)(W + OFF_BCM);
    #pragma unroll
    for (int i = 0; i < 5; i++) cl2[i] = bcm[i];
    #pragma unroll
    for (int p = 0; p < 25; p++) {
      float ha = fast_tanh(acc2[p].x);
      float hb = fast_tanh(acc2[p].y);
      myh[2 * p]     = ha;
      myh[2 * p + 1] = hb;
      const v2f* wra = (const v2f*)(W + OFF_WCM + (2 * p) * CLD);
      const v2f* wrb = (const v2f*)(W + OFF_WCM + (2 * p + 1) * CLD);
      v2f xa; xa.x = ha; xa.y = ha;
      v2f xb; xb.x = hb; xb.y = hb;
      #pragma unroll
      for (int i = 0; i < 5; i++) cl2[i] = pk_fma(wra[i], xa, cl2[i]);
      #pragma unroll
      for (int i = 0; i < 5; i++) cl2[i] = pk_fma(wrb[i], xb, cl2[i]);
    }
  }

  // ---- step 1: pick symbol, aggregate c (also the output c)
  {
    float cl[NSYM];
    #pragma unroll
    for (int i = 0; i < 5; i++) { cl[2 * i] = cl2[i].x; cl[2 * i + 1] = cl2[i].y; }
    w = comm_pick(cl, mk, clp);
  }
  #pragma unroll
  for (int s = 0; s < NSYM; s++) {
    unsigned long long b = __ballot(w == s);
    c_reg[s] = ((b >> sh) & 0x3FFULL) ? 1.f : 0.f;
  }

  // ===== pre2 += c1 @ W_f1[c] + h1 @ W_f1[h] =====
  #pragma unroll
  for (int s = 0; s < NSYM; s++) {
    v2f cv; cv.x = c_reg[s]; cv.y = c_reg[s];
    const v2f* wr = (const v2f*)(W + OFF_W1c + s * LD);
    #pragma unroll
    for (int j = 0; j < 25; j++) pre2[j] = pk_fma(wr[j], cv, pre2[j]);
  }
  #pragma unroll 2
  for (int k = 0; k < HID; k++) {
    float x = myh[k];
    v2f xx; xx.x = x; xx.y = x;
    const v2f* wr = (const v2f*)(W + OFF_W1H + k * LD);
    #pragma unroll
    for (int j = 0; j < 25; j++) pre2[j] = pk_fma(wr[j], xx, pre2[j]);
  }

  // ===== heads fused with final tanh =====
  float l0, l1, bv;
  {
    const v2f* wpi = (const v2f*)(W + OFF_WPI);
    const v2f* wv  = (const v2f*)(W + OFF_WV);
    v2f bpi = *(const v2f*)(W + OFF_BPI);
    l0 = bpi.x; l1 = bpi.y; bv = *(W + OFF_BV);
    #pragma unroll
    for (int p = 0; p < 25; p++) {
      float ha = fast_tanh(pre2[p].x);
      float hb = fast_tanh(pre2[p].y);
      v2f w0 = wpi[2 * p], w1 = wpi[2 * p + 1], wvv = wv[p];
      l0 = fmaf(ha, w0.x, l0); l1 = fmaf(ha, w0.y, l1);
      l0 = fmaf(hb, w1.x, l0); l1 = fmaf(hb, w1.y, l1);
      bv = fmaf(ha, wvv.x, bv); bv = fmaf(hb, wvv.y, bv);
    }
  }

  if (act) {
    float2* o2 = (float2*)out;
    o2[g] = make_float2((mk == 0.f) ? NEGV : l0, (mk == 0.f) ? NEGV : l1);
    out[NA * 2 + g] = bv * mk;
    out[NA * 3 + g] = clp;
    float2* c2 = (float2*)(out + NA * 4);
    const long long cb = g * (NSYM / 2);
    #pragma unroll
    for (int s = 0; s < NSYM / 2; s++)
      c2[cb + s] = make_float2(c_reg[2 * s], c_reg[2 * s + 1]);
  }
}

extern "C" void kernel_launch(void* const* d_in, const int* in_sizes, int n_in,
                              void* d_out, int out_size, void* d_ws, size_t ws_size,
                              hipStream_t stream) {
  const float* obs    = (const float*)d_in[0];
  const float* mask   = (const float*)d_in[1];
  const float* W_enc  = (const float*)d_in[2];
  const float* b_enc  = (const float*)d_in[3];
  const float* W_f    = (const float*)d_in[4];
  const float* b_f    = (const float*)d_in[5];
  const float* W_comm = (const float*)d_in[6];
  const float* b_comm = (const float*)d_in[7];
  const float* W_pi   = (const float*)d_in[8];
  const float* b_pi   = (const float*)d_in[9];
  const float* W_v    = (const float*)d_in[10];
  const float* b_v    = (const float*)d_in[11];
  float* out = (float*)d_out;
  float* ws  = (float*)d_ws;

  const int B = in_sizes[0] / (NAGENT * OBS_D);

  hipLaunchKernelGGL(prep_weights, dim3((NPREP + 255) / 256), dim3(256), 0, stream,
                     W_enc, W_f, W_comm, W_pi, W_v, b_enc, b_f, b_comm, b_pi, b_v, ws);

  const int grid = (B + BPW - 1) / BPW;
  hipLaunchKernelGGL(policy_kernel, dim3(grid), dim3(TPB), 0, stream,
                     obs, mask, ws, out, B);
}

// Round 7
// 705.711 us; speedup vs baseline: 22.3580x; 1.2287x over previous
//
#include <hip/hip_runtime.h>
#include <math.h>

#define NAGENT 10
#define OBS_D  64
#define HID    50
#define NSYM   10
#define NEGV   (-1e9f)

#define TPB 256              // 4 waves share one LDS weight copy
#define WPB 4
#define BPW 6                // batch elements per wave (60 active lanes)
#define BPB (WPB * BPW)      // 24

#define LD  52               // padded row stride (floats) for 50-wide matrices
#define CLD 12               // padded W_comm row stride

// LDS / ws layout (floats):
#define OFF_ENC  0           // [64][52]  W_enc
#define OFF_WC0  3328        // [50][52]  W_f0[h] + W_f0[skip]  (h==h0 at step 0)
#define OFF_W1S  5928        // [50][52]  W_f1[skip]
#define OFF_W1H  8528        // [50][52]  W_f1[h]
#define OFF_WC0c 11128       // [10][52]  W_f0[c]
#define OFF_W1c  11648       // [10][52]  W_f1[c]
#define OFF_WCM  12168       // [50][12]  W_comm
#define OFF_WPI  12768       // [50][2]   W_pi
#define OFF_WV   12868       // [50]      W_v
#define OFF_BENC 12918       // [50]      b_enc
#define OFF_BF   12968       // [2][50]   b_f
#define OFF_BCM  13068       // [10]      b_comm
#define OFF_BPI  13078       // [2]       b_pi
#define OFF_BV   13080       // [1]       b_v
#define NPREP    13084       // 52336 B of LDS

typedef float v2f __attribute__((ext_vector_type(2)));

__device__ __forceinline__ v2f pk_fma(v2f a, v2f b, v2f c) {
  v2f d;
  asm("v_pk_fma_f32 %0, %1, %2, %3" : "=v"(d) : "v"(a), "v"(b), "v"(c));
  return d;
}

__device__ __forceinline__ float fast_tanh(float x) {
  float xc = fminf(15.f, fmaxf(-15.f, x));
  float e  = __expf(2.f * xc);
  return __fdividef(e - 1.f, e + 1.f);
}

__global__ void prep_weights(const float* __restrict__ W_enc,
                             const float* __restrict__ W_f,
                             const float* __restrict__ W_comm,
                             const float* __restrict__ W_pi,
                             const float* __restrict__ W_v,
                             const float* __restrict__ b_enc,
                             const float* __restrict__ b_f,
                             const float* __restrict__ b_comm,
                             const float* __restrict__ b_pi,
                             const float* __restrict__ b_v,
                             float* __restrict__ ws) {
  int i = blockIdx.x * blockDim.x + threadIdx.x;
  if (i >= NPREP) return;
  float v = 0.f;
  if (i < OFF_WCM) {
    int j = i % LD, r = i / LD;
    if (j < HID) {
      if      (r <  64)                 { v = W_enc[r*HID + j]; }
      else if (r < 114) { int k = r-64;   v = W_f[k*HID + j] + W_f[(60+k)*HID + j]; }
      else if (r < 164) { int k = r-114;  v = W_f[(110+60+k)*HID + j]; }
      else if (r < 214) { int k = r-164;  v = W_f[(110+k)*HID + j]; }
      else if (r < 224) { int s = r-214;  v = W_f[(50+s)*HID + j]; }
      else              { int s = r-224;  v = W_f[(110+50+s)*HID + j]; }
    }
  } else if (i < OFF_WPI) {
    int r = (i - OFF_WCM) / CLD, j = (i - OFF_WCM) % CLD;
    v = (j < NSYM) ? W_comm[r*NSYM + j] : 0.f;
  } else if (i < OFF_WV)   { v = W_pi [i - OFF_WPI];
  } else if (i < OFF_BENC) { v = W_v  [i - OFF_WV];
  } else if (i < OFF_BF)   { v = b_enc[i - OFF_BENC];
  } else if (i < OFF_BCM)  { v = b_f  [i - OFF_BF];
  } else if (i < OFF_BPI)  { v = b_comm[i - OFF_BCM];
  } else if (i < OFF_BV)   { v = b_pi [i - OFF_BPI];
  } else if (i == OFF_BV)  { v = b_v[0]; }
  ws[i] = v;
}

__device__ __forceinline__ int comm_pick(float cl[NSYM], float mk, float& clp) {
  #pragma unroll
  for (int s = 0; s < NSYM; s++) cl[s] = (mk == 0.f) ? NEGV : cl[s];
  int w = 0; float best = cl[0];
  #pragma unroll
  for (int s = 1; s < NSYM; s++) { bool b = cl[s] > best; best = b ? cl[s] : best; w = b ? s : w; }
  float se = 0.f;
  #pragma unroll
  for (int s = 0; s < NSYM; s++) se += __expf(cl[s] - best);
  clp += (-__logf(se)) * mk;
  return w;
}

__global__ __launch_bounds__(TPB)
void policy_kernel(const float* __restrict__ obs,
                   const float* __restrict__ mask,
                   const float* __restrict__ wsP,
                   float* __restrict__ out,
                   int B)
{
  __shared__ __align__(16) float lw[NPREP];
  const int t = threadIdx.x;

  // ---- stage all weights/biases into LDS (float4, coalesced), one barrier
  {
    const float4* src = (const float4*)wsP;
    float4* dst = (float4*)lw;
    #pragma unroll 2
    for (int i = t; i < NPREP / 4; i += TPB) dst[i] = src[i];
  }
  __syncthreads();

  const int lane = t & 63;
  const int wv   = t >> 6;
  const int beW  = blockIdx.x * BPB + wv * BPW;
  const int bel  = lane / NAGENT;
  const int aidx = lane % NAGENT;
  const long long NA = (long long)B * NAGENT;
  const bool act = (lane < BPW * NAGENT) && (beW + bel < B);
  const long long g  = (long long)(beW + bel) * NAGENT + aidx;
  const long long gc = act ? g : 0;
  const int sh = bel * NAGENT;

  const float mk = mask[gc];

  // LDS read helpers: all offsets compile-time after unrolling -> ds_read offset:imm
  auto LW2 = [&](int off) -> v2f { return *(const v2f*)&lw[off]; };

  v2f h0v[26];   // h0 floats 0..51 (slot 25 = pad junk, never used at k<50)
  v2f h1v[26];

  // ================= enc: h0 = tanh(obs @ W_enc + b_enc) =================
  {
    float4 ob[16];
    const float4* o4 = (const float4*)(obs + gc * OBS_D);
    #pragma unroll
    for (int q = 0; q < 16; q++) ob[q] = o4[q];

    // chunk 0: j 0..27 (14 v2f); chunk 1: j 28..51 (12 v2f)
    #pragma unroll
    for (int ch = 0; ch < 2; ch++) {
      const int J0  = ch ? 28 : 0;
      const int NJ2 = ch ? 12 : 14;
      v2f acc[14];
      #pragma unroll
      for (int i = 0; i < 14; i++) if (i < NJ2) acc[i] = LW2(OFF_BENC + J0 + 2*i);
      auto row = [&](int k, float x) {
        v2f xx = {x, x};
        #pragma unroll
        for (int i = 0; i < 14; i++) if (i < NJ2)
          acc[i] = pk_fma(LW2(OFF_ENC + k*LD + J0 + 2*i), xx, acc[i]);
      };
      #pragma unroll
      for (int q = 0; q < 16; q++) {
        row(q*4 + 0, ob[q].x); row(q*4 + 1, ob[q].y);
        __builtin_amdgcn_sched_barrier(0);
        row(q*4 + 2, ob[q].z); row(q*4 + 3, ob[q].w);
        __builtin_amdgcn_sched_barrier(0);
      }
      #pragma unroll
      for (int i = 0; i < 14; i++) if (i < NJ2) {
        v2f hh; hh.x = fast_tanh(acc[i].x); hh.y = fast_tanh(acc[i].y);
        h0v[J0/2 + i] = hh;
      }
    }
  }

  auto H0E = [&](int k) -> float { return (k & 1) ? h0v[k/2].y : h0v[k/2].x; };
  auto H1E = [&](int k) -> float { return (k & 1) ? h1v[k/2].y : h1v[k/2].x; };

  float clp = 0.f;
  float c_reg[NSYM];
  int w;

  // ================= step 0 comm head (on h0) =================
  {
    v2f cl2[5];
    #pragma unroll
    for (int i = 0; i < 5; i++) cl2[i] = LW2(OFF_BCM + 2*i);
    #pragma unroll
    for (int k = 0; k < HID; k++) {
      float x = H0E(k);
      v2f xx = {x, x};
      #pragma unroll
      for (int i = 0; i < 5; i++)
        cl2[i] = pk_fma(LW2(OFF_WCM + k*CLD + 2*i), xx, cl2[i]);
      if ((k & 3) == 3) __builtin_amdgcn_sched_barrier(0);
    }
    float cl[NSYM];
    #pragma unroll
    for (int i = 0; i < 5; i++) { cl[2*i] = cl2[i].x; cl[2*i+1] = cl2[i].y; }
    w = comm_pick(cl, mk, clp);
  }
  #pragma unroll
  for (int s = 0; s < NSYM; s++) {
    unsigned long long b = __ballot(w == s);
    c_reg[s] = ((b >> sh) & 0x3FFULL) ? 1.f : 0.f;
  }

  // ===== f0: h1 = tanh(b_f0 + c0 @ W_f0[c] + h0 @ (W_f0[h]+W_f0[skip])) =====
  {
    #pragma unroll
    for (int ch = 0; ch < 2; ch++) {
      const int J0  = ch ? 28 : 0;
      const int NJ2 = ch ? 12 : 14;
      v2f acc[14];
      #pragma unroll
      for (int i = 0; i < 14; i++) if (i < NJ2) acc[i] = LW2(OFF_BF + J0 + 2*i);
      auto row = [&](int base, int k, float x) {
        v2f xx = {x, x};
        #pragma unroll
        for (int i = 0; i < 14; i++) if (i < NJ2)
          acc[i] = pk_fma(LW2(base + k*LD + J0 + 2*i), xx, acc[i]);
      };
      #pragma unroll
      for (int s = 0; s < NSYM; s += 2) {
        row(OFF_WC0c, s, c_reg[s]); row(OFF_WC0c, s+1, c_reg[s+1]);
        __builtin_amdgcn_sched_barrier(0);
      }
      #pragma unroll
      for (int k = 0; k < HID; k += 2) {
        row(OFF_WC0, k, H0E(k)); row(OFF_WC0, k+1, H0E(k+1));
        __builtin_amdgcn_sched_barrier(0);
      }
      #pragma unroll
      for (int i = 0; i < 14; i++) if (i < NJ2) {
        v2f hh; hh.x = fast_tanh(acc[i].x); hh.y = fast_tanh(acc[i].y);
        h1v[J0/2 + i] = hh;
      }
    }
  }

  // ================= step 1 comm head (on h1) =================
  {
    v2f cl2[5];
    #pragma unroll
    for (int i = 0; i < 5; i++) cl2[i] = LW2(OFF_BCM + 2*i);
    #pragma unroll
    for (int k = 0; k < HID; k++) {
      float x = H1E(k);
      v2f xx = {x, x};
      #pragma unroll
      for (int i = 0; i < 5; i++)
        cl2[i] = pk_fma(LW2(OFF_WCM + k*CLD + 2*i), xx, cl2[i]);
      if ((k & 3) == 3) __builtin_amdgcn_sched_barrier(0);
    }
    float cl[NSYM];
    #pragma unroll
    for (int i = 0; i < 5; i++) { cl[2*i] = cl2[i].x; cl[2*i+1] = cl2[i].y; }
    w = comm_pick(cl, mk, clp);
  }
  #pragma unroll
  for (int s = 0; s < NSYM; s++) {
    unsigned long long b = __ballot(w == s);
    c_reg[s] = ((b >> sh) & 0x3FFULL) ? 1.f : 0.f;   // step-1 c (also output c)
  }

  // ===== f1 + heads, 3 j-chunks: pre = b_f1 + c1@W1c + h0@W1S + h1@W1H =====
  float l0 = lw[OFF_BPI], l1 = lw[OFF_BPI + 1], bv = lw[OFF_BV];
  {
    #pragma unroll
    for (int ch = 0; ch < 3; ch++) {
      const int J0  = (ch == 0) ? 0 : (ch == 1 ? 20 : 36);
      const int NJ2 = (ch == 0) ? 10 : 8;
      const int NJR = (ch == 2) ? 14 : NJ2 * 2;   // real (j<50) floats in chunk
      v2f pre[10];
      #pragma unroll
      for (int i = 0; i < 10; i++) if (i < NJ2) pre[i] = LW2(OFF_BF + HID + J0 + 2*i);
      auto row = [&](int base, int k, float x) {
        v2f xx = {x, x};
        #pragma unroll
        for (int i = 0; i < 10; i++) if (i < NJ2)
          pre[i] = pk_fma(LW2(base + k*LD + J0 + 2*i), xx, pre[i]);
      };
      #pragma unroll
      for (int s = 0; s < NSYM; s += 2) {
        row(OFF_W1c, s, c_reg[s]); row(OFF_W1c, s+1, c_reg[s+1]);
        __builtin_amdgcn_sched_barrier(0);
      }
      #pragma unroll
      for (int k = 0; k < HID; k += 2) {
        row(OFF_W1S, k, H0E(k)); row(OFF_W1S, k+1, H0E(k+1));
        __builtin_amdgcn_sched_barrier(0);
      }
      #pragma unroll
      for (int k = 0; k < HID; k += 2) {
        row(OFF_W1H, k, H1E(k)); row(OFF_W1H, k+1, H1E(k+1));
        __builtin_amdgcn_sched_barrier(0);
      }
      #pragma unroll
      for (int i = 0; i < 10; i++) if (i < NJ2) {
        #pragma unroll
        for (int e = 0; e < 2; e++) {
          int jj = 2*i + e;
          if (jj < NJR) {
            int j = J0 + jj;
            float hh = fast_tanh(e ? pre[i].y : pre[i].x);
            v2f wpi = LW2(OFF_WPI + j*2);
            l0 = fmaf(hh, wpi.x, l0);
            l1 = fmaf(hh, wpi.y, l1);
            bv = fmaf(hh, lw[OFF_WV + j], bv);
          }
        }
      }
    }
  }

  if (act) {
    float2* o2 = (float2*)out;
    o2[g] = make_float2((mk == 0.f) ? NEGV : l0, (mk == 0.f) ? NEGV : l1);
    out[NA * 2 + g] = bv * mk;
    out[NA * 3 + g] = clp;
    float2* c2 = (float2*)(out + NA * 4);
    const long long cb = g * (NSYM / 2);
    #pragma unroll
    for (int s = 0; s < NSYM / 2; s++)
      c2[cb + s] = make_float2(c_reg[2 * s], c_reg[2 * s + 1]);
  }
}

extern "C" void kernel_launch(void* const* d_in, const int* in_sizes, int n_in,
                              void* d_out, int out_size, void* d_ws, size_t ws_size,
                              hipStream_t stream) {
  const float* obs    = (const float*)d_in[0];
  const float* mask   = (const float*)d_in[1];
  const float* W_enc  = (const float*)d_in[2];
  const float* b_enc  = (const float*)d_in[3];
  const float* W_f    = (const float*)d_in[4];
  const float* b_f    = (const float*)d_in[5];
  const float* W_comm = (const float*)d_in[6];
  const float* b_comm = (const float*)d_in[7];
  const float* W_pi   = (const float*)d_in[8];
  const float* b_pi   = (const float*)d_in[9];
  const float* W_v    = (const float*)d_in[10];
  const float* b_v    = (const float*)d_in[11];
  float* out = (float*)d_out;
  float* ws  = (float*)d_ws;

  const int B = in_sizes[0] / (NAGENT * OBS_D);

  hipLaunchKernelGGL(prep_weights, dim3((NPREP + 255) / 256), dim3(256), 0, stream,
                     W_enc, W_f, W_comm, W_pi, W_v, b_enc, b_f, b_comm, b_pi, b_v, ws);

  const int grid = (B + BPB - 1) / BPB;
  hipLaunchKernelGGL(policy_kernel, dim3(grid), dim3(TPB), 0, stream,
                     obs, mask, ws, out, B);
}